// Round 8
// baseline (336.045 us; speedup 1.0000x reference)
//
#include <hip/hip_runtime.h>
#include <hip/hip_bf16.h>

#define B_DIM 512
#define T_DIM 512
#define IND 64
#define WIDTH 128
#define GAMMA 0.01f
#define EPS 0.01f

// ---------------------------------------------------------------------------
// Kernel 1: projection  out[m][w] = b[w] + sum_i x[m][i] * V[i][w]
// (unchanged: near BW roofline)
// ---------------------------------------------------------------------------
#define PJ_ROWS 16
#define PJ_NT ((B_DIM * T_DIM) / PJ_ROWS)  // 16384

__global__ __launch_bounds__(256) void proj_kernel(
    const float* __restrict__ x, const float* __restrict__ V,
    const float* __restrict__ bias, float* __restrict__ out) {
  __shared__ __align__(16) float xs[PJ_ROWS * IND];  // 4 KB

  const int tid = threadIdx.x;
  const int c2 = (tid & 63) * 2;
  const int rh = tid >> 6;

  float2 Vreg[IND];
#pragma unroll
  for (int k = 0; k < IND; ++k)
    Vreg[k] = *(const float2*)(V + k * WIDTH + c2);
  const float2 bb = *(const float2*)(bias + c2);

  for (int tile = blockIdx.x; tile < PJ_NT; tile += gridDim.x) {
    const size_t m0 = (size_t)tile * PJ_ROWS;
    __syncthreads();
#pragma unroll
    for (int q = 0; q < 4; ++q)
      xs[tid + 256 * q] = x[m0 * IND + tid + 256 * q];
    __syncthreads();

    float2 acc0 = bb, acc1 = bb, acc2 = bb, acc3 = bb;
#pragma unroll
    for (int k4 = 0; k4 < IND / 4; ++k4) {
      float4 xv0 = ((const float4*)&xs[(rh + 0) * IND])[k4];
      float4 xv1 = ((const float4*)&xs[(rh + 4) * IND])[k4];
      float4 xv2 = ((const float4*)&xs[(rh + 8) * IND])[k4];
      float4 xv3 = ((const float4*)&xs[(rh + 12) * IND])[k4];
#pragma unroll
      for (int j = 0; j < 4; ++j) {
        float2 v = Vreg[4 * k4 + j];
        float e0 = (j == 0) ? xv0.x : (j == 1) ? xv0.y : (j == 2) ? xv0.z : xv0.w;
        float e1 = (j == 0) ? xv1.x : (j == 1) ? xv1.y : (j == 2) ? xv1.z : xv1.w;
        float e2 = (j == 0) ? xv2.x : (j == 1) ? xv2.y : (j == 2) ? xv2.z : xv2.w;
        float e3 = (j == 0) ? xv3.x : (j == 1) ? xv3.y : (j == 2) ? xv3.z : xv3.w;
        acc0.x += e0 * v.x; acc0.y += e0 * v.y;
        acc1.x += e1 * v.x; acc1.y += e1 * v.y;
        acc2.x += e2 * v.x; acc2.y += e2 * v.y;
        acc3.x += e3 * v.x; acc3.y += e3 * v.y;
      }
    }
    *(float2*)(out + (m0 + rh + 0) * WIDTH + c2) = acc0;
    *(float2*)(out + (m0 + rh + 4) * WIDTH + c2) = acc1;
    *(float2*)(out + (m0 + rh + 8) * WIDTH + c2) = acc2;
    *(float2*)(out + (m0 + rh + 12) * WIDTH + c2) = acc3;
  }
}

// ---------------------------------------------------------------------------
// Kernel 2: recurrence = R4 geometry + LDS-only barrier (the untested combo).
// 128 threads/block (2 waves): thread = (col-quad c4 0..31, kc 0..3).
// 4 cols/thread, split-k=4: 128 FMA + 8 ds_read_b128 + DPP reduce per step —
// best issue-efficiency of the series. R4's 1000-cy/step mystery stall is
// attributed to __syncthreads() draining vmcnt(0): the u-prefetch HBM load
// and out-store entered the serial chain with 1 wave/SIMD (nothing to hide
// them). Here the barrier drains lgkmcnt only; global ops stay in flight
// (u[t+2] load is consumed before that address is stored at t+2; out-stores
// are never read by other waves).
// ---------------------------------------------------------------------------
#define LDS_BARRIER() asm volatile("s_waitcnt lgkmcnt(0)\n\ts_barrier" ::: "memory")

template <int CTRL>
__device__ __forceinline__ float dpp_mov(float x) {
  return __int_as_float(
      __builtin_amdgcn_update_dpp(0, __float_as_int(x), CTRL, 0xf, 0xf, true));
}

__global__ __launch_bounds__(128) void rnn_kernel(
    const float* __restrict__ W, const float* __restrict__ init,
    float* __restrict__ out, float* __restrict__ finals) {
  __shared__ __align__(16) float sL[2][WIDTH];
  const int b = blockIdx.x;
  const int tid = threadIdx.x;
  const int kc = tid & 3;    // k-chunk, lane bits 0-1
  const int c4 = tid >> 2;   // 0..31 column quad
  const int c0 = 4 * c4;     // columns c0..c0+3

  // Areg[col][4j+m] = A[kc*32 + ((j+2kc)&7)*4 + m][c0+col],  A = W - W^T
  // (bank-stagger rotation baked in; register indices all compile-time)
  float Areg[4][32];
  {
    const int k0 = kc * 32;
#pragma unroll
    for (int j = 0; j < 8; ++j) {
      const int ri = (j + 2 * kc) & 7;  // runtime, addresses only
      const int k = k0 + ri * 4;
#pragma unroll
      for (int col = 0; col < 4; ++col) {
        const int cc = c0 + col;
        float4 wr = *(const float4*)(W + (size_t)cc * WIDTH + k);  // W[cc][k..]
        Areg[col][4 * j + 0] = W[(size_t)(k + 0) * WIDTH + cc] - wr.x;
        Areg[col][4 * j + 1] = W[(size_t)(k + 1) * WIDTH + cc] - wr.y;
        Areg[col][4 * j + 2] = W[(size_t)(k + 2) * WIDTH + cc] - wr.z;
        Areg[col][4 * j + 3] = W[(size_t)(k + 3) * WIDTH + cc] - wr.w;
      }
    }
  }

  float4 s = *(const float4*)(init + (size_t)b * WIDTH + c0);
  if (kc == 0) *(float4*)&sL[0][c0] = s;
  __syncthreads();

  float* outc = out + (size_t)b * T_DIM * WIDTH + c0;
  float4 u0 = *(const float4*)(outc);
  float4 u1 = *(const float4*)(outc + WIDTH);

#pragma unroll 1
  for (int t = 0; t < T_DIM; ++t) {
    const int p = t & 1;
    const float4 u = u0;
    u0 = u1;
    if (t + 2 < T_DIM) u1 = *(const float4*)(outc + (size_t)(t + 2) * WIDTH);

    const float4* sp = (const float4*)&sL[p][0];
    float a0[4], a1[4];
#pragma unroll
    for (int col = 0; col < 4; ++col) { a0[col] = 0.f; a1[col] = 0.f; }
#pragma unroll
    for (int j = 0; j < 8; ++j) {
      const int ri = (j + 2 * kc) & 7;  // bank-staggered across kc groups
      float4 sv = sp[kc * 8 + ri];
#pragma unroll
      for (int col = 0; col < 4; ++col) {
        a0[col] += sv.x * Areg[col][4 * j + 0];
        a1[col] += sv.y * Areg[col][4 * j + 1];
        a0[col] += sv.z * Areg[col][4 * j + 2];
        a1[col] += sv.w * Areg[col][4 * j + 3];
      }
    }
    float d[4];
#pragma unroll
    for (int col = 0; col < 4; ++col) d[col] = a0[col] + a1[col];
    // 4-way split-k sum over lane bits 0-1 via DPP (pure VALU)
#pragma unroll
    for (int col = 0; col < 4; ++col) d[col] += dpp_mov<0xB1>(d[col]);
#pragma unroll
    for (int col = 0; col < 4; ++col) d[col] += dpp_mov<0x4E>(d[col]);

    float* sa = (float*)&s;
    const float* ua = (const float*)&u;
#pragma unroll
    for (int col = 0; col < 4; ++col) {
      const float f = d[col] - GAMMA * sa[col] + ua[col];
      // tanh(f) = 1 - 2/(exp(2f)+1); inf-safe both directions
      const float e = __expf(2.0f * f);
      const float th = fmaf(-2.0f, __builtin_amdgcn_rcpf(e + 1.0f), 1.0f);
      sa[col] = fmaf(EPS, th, sa[col]);
    }

    if (kc == 0) {
      *(float4*)(outc + (size_t)t * WIDTH) = s;  // overwrite u slot
      *(float4*)&sL[p ^ 1][c0] = s;
    }
    LDS_BARRIER();  // lgkmcnt-only drain: global load/store stay in flight
  }

  if (kc == 0) *(float4*)(finals + (size_t)b * WIDTH + c0) = s;
}

extern "C" void kernel_launch(void* const* d_in, const int* in_sizes, int n_in,
                              void* d_out, int out_size, void* d_ws,
                              size_t ws_size, hipStream_t stream) {
  const float* x = (const float*)d_in[0];
  const float* init = (const float*)d_in[1];
  const float* W = (const float*)d_in[2];
  const float* V = (const float*)d_in[3];
  const float* bias = (const float*)d_in[4];

  float* out = (float*)d_out;
  float* finals = out + (size_t)B_DIM * T_DIM * WIDTH;

  proj_kernel<<<2048, 256, 0, stream>>>(x, V, bias, out);
  rnn_kernel<<<B_DIM, 128, 0, stream>>>(W, init, out, finals);
}